// Round 8
// baseline (32.205 us; speedup 1.0000x reference)
//
#include <hip/hip_runtime.h>
#include <hip/hip_bf16.h>

// MaskedDenseLayer round 8: SINGLE fused kernel (rounds 5-7 all paid a
// ~10us two-kernel tax: dependent-node drain + cross-XCD L2 flush of ws).
// out[b,o] = relu(sum_i x[b,i]*kernel[i,o]*masks[state[b],i,o] + b0[o])
//
// Grid 512 = (state s)*32 + (ot of 32 cols)  -> same-ot blocks land on the
// same XCD (bid%8 = ot%8) so the kern column-slice stays in that L2.
// Block 512 thr = 8 waves = (q: 16-row k-slice of each stage) x (m: m-frag).
// K = 784 = 12 full 64-row stages + 16-row tail. Per stage: 16KB kern+mask
// f32 tiles via global_load_lds dwordx4 (1+1 instr/wave, wave-uniform LDS
// base, 8 rows x 128B each), one barrier; consume: 16 ds_read_b32
// (bank==col -> 2-way only, free) + mul + f2bf + 1 mfma_f32_32x32x16_bf16.
// A-frags (13 bf16x8 / wave) gathered from f32 x BEFORE the loop (overlaps
// stage 0). K-slices reduced via LDS aliased over the tiles; bias+relu store.

#define IN_DIM 784
#define OUT_DIM 1024
#define BS 512

typedef __attribute__((ext_vector_type(8))) short bf16x8;
typedef __attribute__((ext_vector_type(16))) float f32x16;

static __device__ inline short f2bf(float f) {
    __hip_bfloat16 h = __float2bfloat16(f);   // RNE
    short r; __builtin_memcpy(&r, &h, 2); return r;
}

static __device__ inline void gload_lds16(const float* g, float* lds_base_uniform) {
    __builtin_amdgcn_global_load_lds(
        (const __attribute__((address_space(1))) void*)g,
        (__attribute__((address_space(3))) void*)lds_base_uniform, 16, 0, 0);
}

static __device__ inline bf16x8 pack8(float4 a, float4 b) {
    bf16x8 r;
    r[0]=f2bf(a.x); r[1]=f2bf(a.y); r[2]=f2bf(a.z); r[3]=f2bf(a.w);
    r[4]=f2bf(b.x); r[5]=f2bf(b.y); r[6]=f2bf(b.z); r[7]=f2bf(b.w);
    return r;
}

__global__ __launch_bounds__(512, 2) void made_fused(
    const float* __restrict__ x,      // [512, 784]
    const int*   __restrict__ state,  // [512]
    const float* __restrict__ masks,  // [16, 784, 1024]
    const float* __restrict__ kern,   // [784, 1024]
    const float* __restrict__ bias,   // [1024]
    float*       __restrict__ out)    // [512, 1024]
{
    __shared__ float tiles[2][2][64][32];   // [buf][kern/mask][row][col] 32 KB
    __shared__ int   list[BS];
    __shared__ int   cnt;

    const int tid  = threadIdx.x;
    const int lane = tid & 63;
    const int w    = tid >> 6;
    const int q    = w & 3;               // k-slice within each 64-row stage
    const int m    = w >> 2;              // m-frag (rows m*32 .. m*32+31)
    const int bid  = blockIdx.x;
    const int s    = bid >> 5;
    const int ot   = bid & 31;
    const int oc0  = ot * 32;

    const int l31 = lane & 31, khl = lane >> 5;
    const float* mS = masks + (size_t)s * IN_DIM * OUT_DIM;

    // ---- stage a full 64-row tile t into buffer b (1 kern + 1 mask instr/wave)
    auto stageF = [&](int t, int b) {
        const int slot = w * 64 + lane;          // 512 slots x 16B = 8KB/array
        const int row  = slot >> 3, ch = slot & 7;
        const size_t go = (size_t)(t * 64 + row) * OUT_DIM + oc0 + ch * 4;
        gload_lds16(kern + go, &tiles[b][0][0][0] + (size_t)w * 64 * 4);
        gload_lds16(mS   + go, &tiles[b][1][0][0] + (size_t)w * 64 * 4);
    };
    // ---- stage the 16-row tail (rows 768..783): waves 0-1 kern, 2-3 mask
    auto stageT = [&](int b) {
        if (w < 4) {
            const int wi   = w & 1;
            const int slot = wi * 64 + lane;     // 128 slots per array
            const int row  = slot >> 3, ch = slot & 7;
            const size_t go = (size_t)(768 + row) * OUT_DIM + oc0 + ch * 4;
            const float* src = (w < 2) ? kern + go : mS + go;
            float* dst = (w < 2) ? &tiles[b][0][0][0] + (size_t)wi * 64 * 4
                                 : &tiles[b][1][0][0] + (size_t)wi * 64 * 4;
            gload_lds16(src, dst);
        }
    };

    stageF(0, 0);                          // get HBM going immediately
    if (tid == 0) cnt = 0;
    __syncthreads();
    { int st = state[tid]; if (st == s) { int p = atomicAdd(&cnt, 1); list[p] = tid; } }
    __syncthreads();                       // list ready; stage0 drained
    const int ns = cnt;

    float (*red)[3][16][64] = (float (*)[3][16][64])tiles;   // 24KB alias

    for (int mb = 0; mb < ns; mb += 64) {
        // ---- A preload: 13 bf16x8 frags from this lane's gathered x row ----
        int r0 = mb + m * 32 + l31; if (r0 >= ns) r0 = ns - 1;
        const float* xr = x + (size_t)list[r0] * IN_DIM;
        bf16x8 a[13];
#pragma unroll
        for (int t = 0; t < 12; ++t) {
            const int off = t * 64 + q * 16 + khl * 8;
            a[t] = pack8(*(const float4*)(xr + off), *(const float4*)(xr + off + 4));
        }
        a[12] = pack8(*(const float4*)(xr + 768 + khl * 8),
                      *(const float4*)(xr + 772 + khl * 8));

        f32x16 acc;
#pragma unroll
        for (int r = 0; r < 16; ++r) acc[r] = 0.f;

        int cb = 0;
        for (int t = 0; t < 13; ++t) {
            if (t + 1 < 12)      stageF(t + 1, cb ^ 1);
            else if (t + 1 == 12) stageT(cb ^ 1);
            if (t < 12) {
                bf16x8 bfr;
#pragma unroll
                for (int e = 0; e < 8; ++e) {
                    const int row = q * 16 + khl * 8 + e;
                    bfr[e] = f2bf(tiles[cb][0][row][l31] * tiles[cb][1][row][l31]);
                }
                acc = __builtin_amdgcn_mfma_f32_32x32x16_bf16(a[t], bfr, acc, 0, 0, 0);
            } else if (q == 0) {           // tail: k 768..783, q==0 waves only
                bf16x8 bfr;
#pragma unroll
                for (int e = 0; e < 8; ++e) {
                    const int row = khl * 8 + e;
                    bfr[e] = f2bf(tiles[cb][0][row][l31] * tiles[cb][1][row][l31]);
                }
                acc = __builtin_amdgcn_mfma_f32_32x32x16_bf16(a[12], bfr, acc, 0, 0, 0);
            }
            __syncthreads();               // stage t+1 landed; buf cb reusable
            cb ^= 1;
        }

        // ---- reduce 4 k-slices (LDS aliased over tiles), bias+relu store ----
        if (q) {
#pragma unroll
            for (int j = 0; j < 16; ++j) red[m][q - 1][j][lane] = acc[j];
        }
        __syncthreads();
        if (q == 0) {
            const float bv = bias[oc0 + l31];
#pragma unroll
            for (int j = 0; j < 16; ++j) {
                float v = acc[j] + red[m][0][j][lane] + red[m][1][j][lane]
                                 + red[m][2][j][lane];
                const int row = (j & 3) + 8 * (j >> 2) + 4 * khl;  // C/D layout
                const int sr  = mb + m * 32 + row;
                if (sr < ns) {
                    float o = v + bv;
                    out[(size_t)list[sr] * OUT_DIM + oc0 + l31] = o > 0.f ? o : 0.f;
                }
            }
        }
        __syncthreads();                   // tiles reused next chunk
        if (mb + 64 < ns) stageF(0, 0);    // (practically never taken)
        __syncthreads();
    }
}

extern "C" void kernel_launch(void* const* d_in, const int* in_sizes, int n_in,
                              void* d_out, int out_size, void* d_ws, size_t ws_size,
                              hipStream_t stream) {
    (void)in_sizes; (void)n_in; (void)out_size; (void)d_ws; (void)ws_size;
    const float* x     = (const float*)d_in[0];
    const int*   state = (const int*)  d_in[1];
    const float* masks = (const float*)d_in[2];
    const float* kern  = (const float*)d_in[3];
    const float* b0    = (const float*)d_in[4];
    float* out = (float*)d_out;

    made_fused<<<dim3(512), dim3(512), 0, stream>>>(x, state, masks, kern, b0, out);
}